// Round 1
// 1426.704 us; speedup vs baseline: 1.3354x; 1.3354x over previous
//
#include <hip/hip_runtime.h>
#include <cstdint>
#include <cstddef>

#define T_STEPS 12
#define NNODES  10000
#define NEDGES  320000
#define IN_DIM  64
#define HID     128
#define EMB     64
#define G3      192
#define NPAD    10112   // 79*128, decoder tile padding

typedef __attribute__((ext_vector_type(8))) short short8;
typedef __attribute__((ext_vector_type(4))) float f32x4;

// ---------------------------------------------------------------- setup / CSR
__global__ void k_setup(float* __restrict__ deg, int* __restrict__ cnt) {
    int i = blockIdx.x * 256 + threadIdx.x;
    if (i < NNODES) { deg[i] = 1.0f; cnt[i] = 1; }   // self-loop weight 1, count 1
}

__global__ void k_edge(const int* __restrict__ eidx, const float* __restrict__ ew,
                       float* __restrict__ deg, int* __restrict__ cnt) {
    int e = blockIdx.x * 256 + threadIdx.x;
    if (e >= NEDGES) return;
    int c = eidx[NEDGES + e];          // col
    atomicAdd(&deg[c], ew[e]);
    atomicAdd(&cnt[c], 1);
}

__global__ void k_dinv(const float* __restrict__ deg, float* __restrict__ dinv) {
    int i = blockIdx.x * 256 + threadIdx.x;
    if (i >= NNODES) return;
    float d = deg[i];
    dinv[i] = (d > 0.0f) ? rsqrtf(d) : 0.0f;
}

__global__ __launch_bounds__(1024) void k_scan(const int* __restrict__ cnt,
                                               int* __restrict__ offs, int* __restrict__ cursor) {
    __shared__ int sh[1024];
    int t = threadIdx.x;
    int loc[10];
    int run = 0;
#pragma unroll
    for (int i = 0; i < 10; ++i) {
        int idx = t * 10 + i;
        int v = (idx < NNODES) ? cnt[idx] : 0;
        loc[i] = run;
        run += v;
    }
    sh[t] = run;
    __syncthreads();
    for (int off = 1; off < 1024; off <<= 1) {
        int v = 0;
        if (t >= off) v = sh[t - off];
        __syncthreads();
        if (t >= off) sh[t] += v;
        __syncthreads();
    }
    int base = (t > 0) ? sh[t - 1] : 0;
#pragma unroll
    for (int i = 0; i < 10; ++i) {
        int idx = t * 10 + i;
        if (idx < NNODES) {
            int e = base + loc[i];
            offs[idx] = e;
            cursor[idx] = e;
        }
    }
    if (t == 1023) offs[NNODES] = sh[1023];
}

__global__ void k_scatter(const int* __restrict__ eidx, const float* __restrict__ ew,
                          const float* __restrict__ dinv, int* __restrict__ cursor,
                          int* __restrict__ srcb, float* __restrict__ wnb) {
    int e = blockIdx.x * 256 + threadIdx.x;
    if (e < NEDGES) {
        int r = eidx[e];
        int c = eidx[NEDGES + e];
        float w = dinv[r] * ew[e] * dinv[c];
        int p = atomicAdd(&cursor[c], 1);
        srcb[p] = r; wnb[p] = w;
    } else if (e < NEDGES + NNODES) {
        int i = e - NEDGES;
        float di = dinv[i];
        int p = atomicAdd(&cursor[i], 1);
        srcb[p] = i; wnb[p] = di * di;
    }
}

// ---------------------------------------------------------------- small GEMM
// C[M,NO] = A[M,K] @ B + optional bias. BT=true: B stored [K,NO] row-major.
// BT=false: B stored [NO,K] (computes A @ B^T). PERM: output row r -> (r%N)*12 + r/N.
template <int K, int NO, int GR, int RPT, bool BT, bool BIAS, bool PERM>
__global__ __launch_bounds__(NO* GR) void k_mm(const float* __restrict__ A,
                                               const float* __restrict__ B,
                                               const float* __restrict__ bias,
                                               float* __restrict__ C, int M) {
    constexpr int NOP = NO + 1;
    __shared__ float Bs[K * NOP];   // [k][c]
    const int tid = threadIdx.x;
    constexpr int NTHR = NO * GR;
    for (int i = tid; i < K * NO; i += NTHR) {
        if (BT) { int k = i / NO, c = i - k * NO; Bs[k * NOP + c] = B[i]; }
        else    { int c = i / K,  k = i - c * K;  Bs[k * NOP + c] = B[i]; }
    }
    __syncthreads();
    const int c  = tid % NO;
    const int rg = tid / NO;
    const float bv = BIAS ? bias[c] : 0.0f;
    for (int r0 = (blockIdx.x * GR + rg) * RPT; r0 < M; r0 += gridDim.x * GR * RPT) {
        int r0u = __builtin_amdgcn_readfirstlane(r0);
        float acc[RPT];
#pragma unroll
        for (int i = 0; i < RPT; ++i) acc[i] = bv;
        const float4* A4 = (const float4*)A + (size_t)r0u * (K / 4);
        for (int k0 = 0; k0 < K; k0 += 4) {
            float a[RPT][4];
#pragma unroll
            for (int i = 0; i < RPT; ++i) {
                float4 v = A4[i * (K / 4) + (k0 >> 2)];
                a[i][0] = v.x; a[i][1] = v.y; a[i][2] = v.z; a[i][3] = v.w;
            }
#pragma unroll
            for (int j = 0; j < 4; ++j) {
                float b = Bs[(k0 + j) * NOP + c];
#pragma unroll
                for (int i = 0; i < RPT; ++i) acc[i] = fmaf(a[i][j], b, acc[i]);
            }
        }
#pragma unroll
        for (int i = 0; i < RPT; ++i) {
            int rr = r0 + i;
            size_t orow = PERM ? ((size_t)(rr % NNODES) * T_STEPS + rr / NNODES) : (size_t)rr;
            C[orow * NO + c] = acc[i];
        }
    }
}

// ---------------------------------------------------------------- aggregation
// Node-major layout: H rows are [node][t][F]. One wave per node, all 12 t at once.
template <int F, bool RELU>
__global__ __launch_bounds__(256) void k_agg(const float* __restrict__ H,
                                             const int* __restrict__ srcb,
                                             const float* __restrict__ wnb,
                                             const int* __restrict__ offs,
                                             const float* __restrict__ bias,
                                             float* __restrict__ out) {
    int node = (blockIdx.x * 256 + threadIdx.x) >> 6;
    node = __builtin_amdgcn_readfirstlane(node);
    if (node >= NNODES) return;
    int lane = threadIdx.x & 63;
    int beg = offs[node], end = offs[node + 1];
    if (F == 128) {
        const float2* H2 = (const float2*)H;
        float2 bv = ((const float2*)bias)[lane];
        float2 acc[T_STEPS];
#pragma unroll
        for (int t = 0; t < T_STEPS; ++t) acc[t] = bv;
        for (int e0 = beg; e0 < end; e0 += 64) {
            int idx = e0 + lane;
            int sv = (idx < end) ? srcb[idx] : 0;
            float wv = (idx < end) ? wnb[idx] : 0.0f;
            int m = min(64, end - e0);
            for (int j = 0; j < m; ++j) {
                int sj = __shfl(sv, j);
                float wj = __shfl(wv, j);
                size_t base = (size_t)sj * (T_STEPS * 64);
#pragma unroll
                for (int t = 0; t < T_STEPS; ++t) {
                    float2 hv = H2[base + t * 64 + lane];
                    acc[t].x = fmaf(wj, hv.x, acc[t].x);
                    acc[t].y = fmaf(wj, hv.y, acc[t].y);
                }
            }
        }
        float2* O2 = (float2*)out;
#pragma unroll
        for (int t = 0; t < T_STEPS; ++t) {
            float2 a = acc[t];
            if (RELU) { a.x = fmaxf(a.x, 0.0f); a.y = fmaxf(a.y, 0.0f); }
            O2[((size_t)node * T_STEPS + t) * 64 + lane] = a;
        }
    } else {
        float bv = bias[lane];
        float acc[T_STEPS];
#pragma unroll
        for (int t = 0; t < T_STEPS; ++t) acc[t] = bv;
        for (int e0 = beg; e0 < end; e0 += 64) {
            int idx = e0 + lane;
            int sv = (idx < end) ? srcb[idx] : 0;
            float wv = (idx < end) ? wnb[idx] : 0.0f;
            int m = min(64, end - e0);
            for (int j = 0; j < m; ++j) {
                int sj = __shfl(sv, j);
                float wj = __shfl(wv, j);
                size_t base = (size_t)sj * (T_STEPS * 64);
#pragma unroll
                for (int t = 0; t < T_STEPS; ++t) {
                    acc[t] = fmaf(wj, H[base + t * 64 + lane], acc[t]);
                }
            }
        }
#pragma unroll
        for (int t = 0; t < T_STEPS; ++t) {
            float a = acc[t];
            if (RELU) a = fmaxf(a, 0.0f);
            out[((size_t)node * T_STEPS + t) * 64 + lane] = a;
        }
    }
}

// ---------------------------------------------------------------- fused GRU (all 12 steps)
// gi layout: [node][t][192]. Each block owns RPB=6 rows for the whole sequence.
// W_hh row lives in REGISTERS (one output column c per thread, t-invariant).
// hs stride 64 (broadcast reads have no bank conflicts; enables ds_read_b128).
__global__ __launch_bounds__(192, 3) void k_gru(const float* __restrict__ gi,
                                                const float* __restrict__ W_hh,  // [192,64]
                                                const float* __restrict__ b_hh,
                                                float* __restrict__ hout) {      // [N,64]
    constexpr int RPB = 6;
    __shared__ float ghs[RPB][G3 + 1];   // 4632 B
    __shared__ float hs[RPB][64];        // 1536 B  -> total 6168 B
    int tid = threadIdx.x;
    // hoist this thread's W_hh row (64 floats) into registers, t-invariant
    float wv[64];
    const float4* W4 = (const float4*)(W_hh + (size_t)tid * 64);
#pragma unroll
    for (int j = 0; j < 16; ++j) {
        float4 v = W4[j];
        wv[4 * j + 0] = v.x; wv[4 * j + 1] = v.y;
        wv[4 * j + 2] = v.z; wv[4 * j + 3] = v.w;
    }
    for (int i = tid; i < RPB * 64; i += 192) ((float*)hs)[i] = 0.0f;
    __syncthreads();
    int r0 = blockIdx.x * RPB;
    float bh = b_hh[tid];
    for (int t = 0; t < T_STEPS; ++t) {
        float acc[RPB];
#pragma unroll
        for (int i = 0; i < RPB; ++i) acc[i] = bh;
#pragma unroll
        for (int k0 = 0; k0 < 64; k0 += 4) {
#pragma unroll
            for (int i = 0; i < RPB; ++i) {
                float4 h4 = *(const float4*)&hs[i][k0];   // broadcast ds_read_b128
                acc[i] = fmaf(h4.x, wv[k0 + 0], acc[i]);
                acc[i] = fmaf(h4.y, wv[k0 + 1], acc[i]);
                acc[i] = fmaf(h4.z, wv[k0 + 2], acc[i]);
                acc[i] = fmaf(h4.w, wv[k0 + 3], acc[i]);
            }
        }
#pragma unroll
        for (int i = 0; i < RPB; ++i) ghs[i][tid] = acc[i];
        __syncthreads();
#pragma unroll
        for (int it = 0; it < 2; ++it) {
            int item = it * 192 + tid;        // 0..383, exactly 2 full passes
            int rr = item >> 6, f = item & 63;
            int grow = r0 + rr;
            if (grow < NNODES) {
                const float* gir = gi + ((size_t)grow * T_STEPS + t) * G3;
                float ir = gir[f], iz = gir[64 + f], inn = gir[128 + f];
                float hr = ghs[rr][f], hz = ghs[rr][64 + f], hn = ghs[rr][128 + f];
                float rg = 1.0f / (1.0f + expf(-(ir + hr)));
                float zg = 1.0f / (1.0f + expf(-(iz + hz)));
                float ng = tanhf(fmaf(rg, hn, inn));
                float hp = hs[rr][f];
                hs[rr][f] = fmaf(zg, hp - ng, ng);    // (1-z)*n + z*h
            }
        }
        __syncthreads();
    }
#pragma unroll
    for (int it = 0; it < 2; ++it) {
        int item = it * 192 + tid;
        int rr = item >> 6, f = item & 63;
        int grow = r0 + rr;
        if (grow < NNODES) hout[(size_t)grow * 64 + f] = hs[rr][f];
    }
}

__global__ void k_zcopy(const float* __restrict__ h, float* __restrict__ out) {
    int i = blockIdx.x * 256 + threadIdx.x;
    if (i < NNODES * EMB) out[(size_t)NNODES * NNODES + i] = h[i];
}

// ---------------------------------------------------------------- bf16 hi/lo split
__global__ void k_zsplit(const float* __restrict__ h,
                         unsigned short* __restrict__ zhi, unsigned short* __restrict__ zlo) {
    int i = blockIdx.x * 256 + threadIdx.x;
    if (i >= NPAD * EMB) return;
    float x = (i < NNODES * EMB) ? h[i] : 0.0f;
    uint32_t b = __float_as_uint(x);
    uint32_t rh = (b + 0x7FFFu + ((b >> 16) & 1u)) & 0xFFFF0000u;   // RNE bf16 of x
    float fhi = __uint_as_float(rh);
    float lo = x - fhi;
    uint32_t bl = __float_as_uint(lo);
    uint32_t rl = (bl + 0x7FFFu + ((bl >> 16) & 1u)) & 0xFFFF0000u;
    zhi[i] = (unsigned short)(rh >> 16);
    zlo[i] = (unsigned short)(rl >> 16);
}

// ---------------------------------------------------------------- decoder (MFMA, K=192 hi/lo trick)
__device__ __forceinline__ float softplusf(float x) {
    return fmaxf(x, 0.0f) + log1pf(expf(-fabsf(x)));
}

__global__ __launch_bounds__(256) void k_dec(const unsigned short* __restrict__ zhi,
                                             const unsigned short* __restrict__ zlo,
                                             const float* __restrict__ dbias,
                                             float* __restrict__ out) {
    // LDS: per tile 128 rows x 128 bf16 (hi 64 | lo 64), 16B chunks XOR-swizzled by row&15.
    __shared__ short As[128 * 128];
    __shared__ short Bs[128 * 128];
    int tid = threadIdx.x;
    int r0 = blockIdx.y * 128, c0 = blockIdx.x * 128;
    const float4* zh4 = (const float4*)zhi;
    const float4* zl4 = (const float4*)zlo;
#pragma unroll
    for (int p8 = 0; p8 < 8; ++p8) {
        int idx = p8 * 256 + tid;
        int row = idx >> 4, c = idx & 15;
        float4 va = (c < 8) ? zh4[(size_t)(r0 + row) * 8 + c] : zl4[(size_t)(r0 + row) * 8 + (c - 8)];
        float4 vb = (c < 8) ? zh4[(size_t)(c0 + row) * 8 + c] : zl4[(size_t)(c0 + row) * 8 + (c - 8)];
        int pos = c ^ (row & 15);
        *(float4*)&As[row * 128 + pos * 8] = va;
        *(float4*)&Bs[row * 128 + pos * 8] = vb;
    }
    __syncthreads();
    int lane = tid & 63, w = tid >> 6;
    int r = lane & 15, q = lane >> 4;
    f32x4 acc[2][8];
#pragma unroll
    for (int mt = 0; mt < 2; ++mt)
#pragma unroll
        for (int nt = 0; nt < 8; ++nt) acc[mt][nt] = (f32x4){0.f, 0.f, 0.f, 0.f};
    // K=192: A chunks [hi0,hi1,hi0,hi1,lo0,lo1] ; B chunks [hi0,hi1,lo0,lo1,hi0,hi1]
    const int aSel[6] = {0, 4, 0, 4, 8, 12};
    const int bSel[6] = {0, 4, 8, 12, 0, 4};
#pragma unroll
    for (int ks = 0; ks < 6; ++ks) {
        short8 af[2], bf[8];
#pragma unroll
        for (int mt = 0; mt < 2; ++mt) {
            int rowA = w * 32 + mt * 16 + r;
            af[mt] = *(const short8*)&As[rowA * 128 + ((aSel[ks] + q) ^ r) * 8];
        }
#pragma unroll
        for (int nt = 0; nt < 8; ++nt) {
            int rowB = nt * 16 + r;
            bf[nt] = *(const short8*)&Bs[rowB * 128 + ((bSel[ks] + q) ^ r) * 8];
        }
#pragma unroll
        for (int mt = 0; mt < 2; ++mt)
#pragma unroll
            for (int nt = 0; nt < 8; ++nt)
                acc[mt][nt] = __builtin_amdgcn_mfma_f32_16x16x32_bf16(af[mt], bf[nt], acc[mt][nt], 0, 0, 0);
    }
    float db = dbias[0];
    bool full = (r0 + 128 <= NNODES) && (c0 + 128 <= NNODES);
    if (full) {
#pragma unroll
        for (int mt = 0; mt < 2; ++mt) {
            int rgb = r0 + w * 32 + mt * 16 + q * 4;
#pragma unroll
            for (int nt = 0; nt < 8; ++nt) {
                int cg = c0 + nt * 16 + r;
#pragma unroll
                for (int reg = 0; reg < 4; ++reg)
                    out[(size_t)(rgb + reg) * NNODES + cg] = softplusf(acc[mt][nt][reg] + db);
            }
        }
    } else {
        for (int mt = 0; mt < 2; ++mt) {
            int rgb = r0 + w * 32 + mt * 16 + q * 4;
            for (int nt = 0; nt < 8; ++nt) {
                int cg = c0 + nt * 16 + r;
                if (cg >= NNODES) continue;
                for (int reg = 0; reg < 4; ++reg) {
                    if (rgb + reg < NNODES)
                        out[(size_t)(rgb + reg) * NNODES + cg] = softplusf(acc[mt][nt][reg] + db);
                }
            }
        }
    }
}

// ---------------------------------------------------------------- launch
extern "C" void kernel_launch(void* const* d_in, const int* in_sizes, int n_in,
                              void* d_out, int out_size, void* d_ws, size_t ws_size,
                              hipStream_t stream) {
    const float* x_seq = (const float*)d_in[0];
    const int*   eidx  = (const int*)d_in[1];
    const float* ew    = (const float*)d_in[2];
    const float* W1    = (const float*)d_in[3];
    const float* b1    = (const float*)d_in[4];
    const float* W2    = (const float*)d_in[5];
    const float* b2    = (const float*)d_in[6];
    const float* W_ih  = (const float*)d_in[7];
    const float* W_hh  = (const float*)d_in[8];
    const float* b_ih  = (const float*)d_in[9];
    const float* b_hh  = (const float*)d_in[10];
    const float* dbias = (const float*)d_in[11];
    float* out = (float*)d_out;

    char* wsp = (char*)d_ws;
    auto alloc = [&](size_t bytes) {
        char* p = wsp;
        wsp += (bytes + 255) & ~(size_t)255;
        return p;
    };
    float* deg    = (float*)alloc((size_t)NNODES * 4);
    float* dinv   = (float*)alloc((size_t)NNODES * 4);
    int*   cnt    = (int*)alloc((size_t)NNODES * 4);
    int*   offs   = (int*)alloc((size_t)(NNODES + 1) * 4);
    int*   cursor = (int*)alloc((size_t)NNODES * 4);
    int*   srcb   = (int*)alloc((size_t)(NEDGES + NNODES) * 4);
    float* wnb    = (float*)alloc((size_t)(NEDGES + NNODES) * 4);
    float* hst    = (float*)alloc((size_t)NNODES * EMB * 4);
    unsigned short* zhi = (unsigned short*)alloc((size_t)NPAD * EMB * 2);
    unsigned short* zlo = (unsigned short*)alloc((size_t)NPAD * EMB * 2);
    float* Buf1   = (float*)alloc((size_t)T_STEPS * NNODES * G3 * 4);   // 92.2 MB
    float* Buf2   = (float*)alloc((size_t)T_STEPS * NNODES * HID * 4);  // 61.4 MB

    const int M = T_STEPS * NNODES;   // 120000

    k_setup<<<(NNODES + 255) / 256, 256, 0, stream>>>(deg, cnt);
    k_edge<<<(NEDGES + 255) / 256, 256, 0, stream>>>(eidx, ew, deg, cnt);
    k_dinv<<<(NNODES + 255) / 256, 256, 0, stream>>>(deg, dinv);
    k_scan<<<1, 1024, 0, stream>>>(cnt, offs, cursor);
    k_scatter<<<(NEDGES + NNODES + 255) / 256, 256, 0, stream>>>(eidx, ew, dinv, cursor, srcb, wnb);

    // GCN layer 1: Buf1 = x@W1 (rows permuted to [n][t]); Buf2 = relu(agg(Buf1)+b1)
    k_mm<64, 128, 2, 8, true, false, true><<<1024, 256, 0, stream>>>(x_seq, W1, nullptr, Buf1, M);
    k_agg<128, true><<<(NNODES * 64 + 255) / 256, 256, 0, stream>>>(Buf1, srcb, wnb, offs, b1, Buf2);
    // GCN layer 2: Buf1 = Buf2@W2 ; Buf2 = agg(Buf1)+b2  (= z_seq, [n][t][64])
    k_mm<128, 64, 4, 8, true, false, false><<<1024, 256, 0, stream>>>(Buf2, W2, nullptr, Buf1, M);
    k_agg<64, false><<<(NNODES * 64 + 255) / 256, 256, 0, stream>>>(Buf1, srcb, wnb, offs, b2, Buf2);
    // GRU input gates for all t: Buf1 = z_seq @ W_ih^T + b_ih  [n][t][192]
    k_mm<64, 192, 1, 8, false, true, false><<<1024, 192, 0, stream>>>(Buf2, W_ih, b_ih, Buf1, M);
    // Fused 12-step GRU, h resident in LDS, W_hh in registers
    k_gru<<<(NNODES + 5) / 6, 192, 0, stream>>>(Buf1, W_hh, b_hh, hst);
    k_zcopy<<<(NNODES * EMB + 255) / 256, 256, 0, stream>>>(hst, out);
    k_zsplit<<<(NPAD * EMB + 255) / 256, 256, 0, stream>>>(hst, zhi, zlo);
    dim3 gdec(NPAD / 128, NPAD / 128);
    k_dec<<<gdec, 256, 0, stream>>>(zhi, zlo, dbias, out);
}

// Round 2
// 1283.087 us; speedup vs baseline: 1.4849x; 1.1119x over previous
//
#include <hip/hip_runtime.h>
#include <cstdint>
#include <cstddef>

#define T_STEPS 12
#define NNODES  10000
#define NEDGES  320000
#define IN_DIM  64
#define HID     128
#define EMB     64
#define G3      192
#define NPAD    10112   // 79*128, decoder tile padding

typedef __attribute__((ext_vector_type(8))) short short8;
typedef __attribute__((ext_vector_type(4))) float f32x4;

// ---------------------------------------------------------------- setup / CSR
__global__ void k_setup(float* __restrict__ deg, int* __restrict__ cnt) {
    int i = blockIdx.x * 256 + threadIdx.x;
    if (i < NNODES) { deg[i] = 1.0f; cnt[i] = 1; }   // self-loop weight 1, count 1
}

__global__ void k_edge(const int* __restrict__ eidx, const float* __restrict__ ew,
                       float* __restrict__ deg, int* __restrict__ cnt) {
    int e = blockIdx.x * 256 + threadIdx.x;
    if (e >= NEDGES) return;
    int c = eidx[NEDGES + e];          // col
    atomicAdd(&deg[c], ew[e]);
    atomicAdd(&cnt[c], 1);
}

__global__ void k_dinv(const float* __restrict__ deg, float* __restrict__ dinv) {
    int i = blockIdx.x * 256 + threadIdx.x;
    if (i >= NNODES) return;
    float d = deg[i];
    dinv[i] = (d > 0.0f) ? rsqrtf(d) : 0.0f;
}

__global__ __launch_bounds__(1024) void k_scan(const int* __restrict__ cnt,
                                               int* __restrict__ offs, int* __restrict__ cursor) {
    __shared__ int sh[1024];
    int t = threadIdx.x;
    int loc[10];
    int run = 0;
#pragma unroll
    for (int i = 0; i < 10; ++i) {
        int idx = t * 10 + i;
        int v = (idx < NNODES) ? cnt[idx] : 0;
        loc[i] = run;
        run += v;
    }
    sh[t] = run;
    __syncthreads();
    for (int off = 1; off < 1024; off <<= 1) {
        int v = 0;
        if (t >= off) v = sh[t - off];
        __syncthreads();
        if (t >= off) sh[t] += v;
        __syncthreads();
    }
    int base = (t > 0) ? sh[t - 1] : 0;
#pragma unroll
    for (int i = 0; i < 10; ++i) {
        int idx = t * 10 + i;
        if (idx < NNODES) {
            int e = base + loc[i];
            offs[idx] = e;
            cursor[idx] = e;
        }
    }
    if (t == 1023) offs[NNODES] = sh[1023];
}

__global__ void k_scatter(const int* __restrict__ eidx, const float* __restrict__ ew,
                          const float* __restrict__ dinv, int* __restrict__ cursor,
                          int* __restrict__ srcb, float* __restrict__ wnb) {
    int e = blockIdx.x * 256 + threadIdx.x;
    if (e < NEDGES) {
        int r = eidx[e];
        int c = eidx[NEDGES + e];
        float w = dinv[r] * ew[e] * dinv[c];
        int p = atomicAdd(&cursor[c], 1);
        srcb[p] = r; wnb[p] = w;
    } else if (e < NEDGES + NNODES) {
        int i = e - NEDGES;
        float di = dinv[i];
        int p = atomicAdd(&cursor[i], 1);
        srcb[p] = i; wnb[p] = di * di;
    }
}

// ---------------------------------------------------------------- small GEMM
// C[M,NO] = A[M,K] @ B + optional bias. BT=true: B stored [K,NO] row-major.
// BT=false: B stored [NO,K] (computes A @ B^T). PERM: output row r -> (r%N)*12 + r/N.
template <int K, int NO, int GR, int RPT, bool BT, bool BIAS, bool PERM>
__global__ __launch_bounds__(NO* GR) void k_mm(const float* __restrict__ A,
                                               const float* __restrict__ B,
                                               const float* __restrict__ bias,
                                               float* __restrict__ C, int M) {
    constexpr int NOP = NO + 1;
    __shared__ float Bs[K * NOP];   // [k][c]
    const int tid = threadIdx.x;
    constexpr int NTHR = NO * GR;
    for (int i = tid; i < K * NO; i += NTHR) {
        if (BT) { int k = i / NO, c = i - k * NO; Bs[k * NOP + c] = B[i]; }
        else    { int c = i / K,  k = i - c * K;  Bs[k * NOP + c] = B[i]; }
    }
    __syncthreads();
    const int c  = tid % NO;
    const int rg = tid / NO;
    const float bv = BIAS ? bias[c] : 0.0f;
    for (int r0 = (blockIdx.x * GR + rg) * RPT; r0 < M; r0 += gridDim.x * GR * RPT) {
        int r0u = __builtin_amdgcn_readfirstlane(r0);
        float acc[RPT];
#pragma unroll
        for (int i = 0; i < RPT; ++i) acc[i] = bv;
        const float4* A4 = (const float4*)A + (size_t)r0u * (K / 4);
        for (int k0 = 0; k0 < K; k0 += 4) {
            float a[RPT][4];
#pragma unroll
            for (int i = 0; i < RPT; ++i) {
                float4 v = A4[i * (K / 4) + (k0 >> 2)];
                a[i][0] = v.x; a[i][1] = v.y; a[i][2] = v.z; a[i][3] = v.w;
            }
#pragma unroll
            for (int j = 0; j < 4; ++j) {
                float b = Bs[(k0 + j) * NOP + c];
#pragma unroll
                for (int i = 0; i < RPT; ++i) acc[i] = fmaf(a[i][j], b, acc[i]);
            }
        }
#pragma unroll
        for (int i = 0; i < RPT; ++i) {
            int rr = r0 + i;
            size_t orow = PERM ? ((size_t)(rr % NNODES) * T_STEPS + rr / NNODES) : (size_t)rr;
            C[orow * NO + c] = acc[i];
        }
    }
}

// ---------------------------------------------------------------- aggregation
// Node-major layout: H rows are [node][t][F]. One wave per node, all 12 t at once.
template <int F, bool RELU>
__global__ __launch_bounds__(256) void k_agg(const float* __restrict__ H,
                                             const int* __restrict__ srcb,
                                             const float* __restrict__ wnb,
                                             const int* __restrict__ offs,
                                             const float* __restrict__ bias,
                                             float* __restrict__ out) {
    int node = (blockIdx.x * 256 + threadIdx.x) >> 6;
    node = __builtin_amdgcn_readfirstlane(node);
    if (node >= NNODES) return;
    int lane = threadIdx.x & 63;
    int beg = offs[node], end = offs[node + 1];
    if (F == 128) {
        const float2* H2 = (const float2*)H;
        float2 bv = ((const float2*)bias)[lane];
        float2 acc[T_STEPS];
#pragma unroll
        for (int t = 0; t < T_STEPS; ++t) acc[t] = bv;
        for (int e0 = beg; e0 < end; e0 += 64) {
            int idx = e0 + lane;
            int sv = (idx < end) ? srcb[idx] : 0;
            float wv = (idx < end) ? wnb[idx] : 0.0f;
            int m = min(64, end - e0);
            for (int j = 0; j < m; ++j) {
                int sj = __shfl(sv, j);
                float wj = __shfl(wv, j);
                size_t base = (size_t)sj * (T_STEPS * 64);
#pragma unroll
                for (int t = 0; t < T_STEPS; ++t) {
                    float2 hv = H2[base + t * 64 + lane];
                    acc[t].x = fmaf(wj, hv.x, acc[t].x);
                    acc[t].y = fmaf(wj, hv.y, acc[t].y);
                }
            }
        }
        float2* O2 = (float2*)out;
#pragma unroll
        for (int t = 0; t < T_STEPS; ++t) {
            float2 a = acc[t];
            if (RELU) { a.x = fmaxf(a.x, 0.0f); a.y = fmaxf(a.y, 0.0f); }
            O2[((size_t)node * T_STEPS + t) * 64 + lane] = a;
        }
    } else {
        float bv = bias[lane];
        float acc[T_STEPS];
#pragma unroll
        for (int t = 0; t < T_STEPS; ++t) acc[t] = bv;
        for (int e0 = beg; e0 < end; e0 += 64) {
            int idx = e0 + lane;
            int sv = (idx < end) ? srcb[idx] : 0;
            float wv = (idx < end) ? wnb[idx] : 0.0f;
            int m = min(64, end - e0);
            for (int j = 0; j < m; ++j) {
                int sj = __shfl(sv, j);
                float wj = __shfl(wv, j);
                size_t base = (size_t)sj * (T_STEPS * 64);
#pragma unroll
                for (int t = 0; t < T_STEPS; ++t) {
                    acc[t] = fmaf(wj, H[base + t * 64 + lane], acc[t]);
                }
            }
        }
#pragma unroll
        for (int t = 0; t < T_STEPS; ++t) {
            float a = acc[t];
            if (RELU) a = fmaxf(a, 0.0f);
            out[((size_t)node * T_STEPS + t) * 64 + lane] = a;
        }
    }
}

// ---------------------------------------------------------------- fused GRU (all 12 steps)
// gi layout: [node][t][192]. Each block owns RPB=6 rows for the whole sequence.
// W_hh row lives in REGISTERS (one output column c per thread, t-invariant).
// hs stride 64 (broadcast reads have no bank conflicts; enables ds_read_b128).
__global__ __launch_bounds__(192, 3) void k_gru(const float* __restrict__ gi,
                                                const float* __restrict__ W_hh,  // [192,64]
                                                const float* __restrict__ b_hh,
                                                float* __restrict__ hout) {      // [N,64]
    constexpr int RPB = 6;
    __shared__ float ghs[RPB][G3 + 1];   // 4632 B
    __shared__ float hs[RPB][64];        // 1536 B  -> total 6168 B
    int tid = threadIdx.x;
    // hoist this thread's W_hh row (64 floats) into registers, t-invariant
    float wv[64];
    const float4* W4 = (const float4*)(W_hh + (size_t)tid * 64);
#pragma unroll
    for (int j = 0; j < 16; ++j) {
        float4 v = W4[j];
        wv[4 * j + 0] = v.x; wv[4 * j + 1] = v.y;
        wv[4 * j + 2] = v.z; wv[4 * j + 3] = v.w;
    }
    for (int i = tid; i < RPB * 64; i += 192) ((float*)hs)[i] = 0.0f;
    __syncthreads();
    int r0 = blockIdx.x * RPB;
    float bh = b_hh[tid];
    for (int t = 0; t < T_STEPS; ++t) {
        float acc[RPB];
#pragma unroll
        for (int i = 0; i < RPB; ++i) acc[i] = bh;
#pragma unroll
        for (int k0 = 0; k0 < 64; k0 += 4) {
#pragma unroll
            for (int i = 0; i < RPB; ++i) {
                float4 h4 = *(const float4*)&hs[i][k0];   // broadcast ds_read_b128
                acc[i] = fmaf(h4.x, wv[k0 + 0], acc[i]);
                acc[i] = fmaf(h4.y, wv[k0 + 1], acc[i]);
                acc[i] = fmaf(h4.z, wv[k0 + 2], acc[i]);
                acc[i] = fmaf(h4.w, wv[k0 + 3], acc[i]);
            }
        }
#pragma unroll
        for (int i = 0; i < RPB; ++i) ghs[i][tid] = acc[i];
        __syncthreads();
#pragma unroll
        for (int it = 0; it < 2; ++it) {
            int item = it * 192 + tid;        // 0..383, exactly 2 full passes
            int rr = item >> 6, f = item & 63;
            int grow = r0 + rr;
            if (grow < NNODES) {
                const float* gir = gi + ((size_t)grow * T_STEPS + t) * G3;
                float ir = gir[f], iz = gir[64 + f], inn = gir[128 + f];
                float hr = ghs[rr][f], hz = ghs[rr][64 + f], hn = ghs[rr][128 + f];
                float rg = 1.0f / (1.0f + expf(-(ir + hr)));
                float zg = 1.0f / (1.0f + expf(-(iz + hz)));
                float ng = tanhf(fmaf(rg, hn, inn));
                float hp = hs[rr][f];
                hs[rr][f] = fmaf(zg, hp - ng, ng);    // (1-z)*n + z*h
            }
        }
        __syncthreads();
    }
#pragma unroll
    for (int it = 0; it < 2; ++it) {
        int item = it * 192 + tid;
        int rr = item >> 6, f = item & 63;
        int grow = r0 + rr;
        if (grow < NNODES) hout[(size_t)grow * 64 + f] = hs[rr][f];
    }
}

__global__ void k_zcopy(const float* __restrict__ h, float* __restrict__ out) {
    int i = blockIdx.x * 256 + threadIdx.x;
    if (i < NNODES * EMB) out[(size_t)NNODES * NNODES + i] = h[i];
}

// ---------------------------------------------------------------- bf16 hi/lo split
__global__ void k_zsplit(const float* __restrict__ h,
                         unsigned short* __restrict__ zhi, unsigned short* __restrict__ zlo) {
    int i = blockIdx.x * 256 + threadIdx.x;
    if (i >= NPAD * EMB) return;
    float x = (i < NNODES * EMB) ? h[i] : 0.0f;
    uint32_t b = __float_as_uint(x);
    uint32_t rh = (b + 0x7FFFu + ((b >> 16) & 1u)) & 0xFFFF0000u;   // RNE bf16 of x
    float fhi = __uint_as_float(rh);
    float lo = x - fhi;
    uint32_t bl = __float_as_uint(lo);
    uint32_t rl = (bl + 0x7FFFu + ((bl >> 16) & 1u)) & 0xFFFF0000u;
    zhi[i] = (unsigned short)(rh >> 16);
    zlo[i] = (unsigned short)(rl >> 16);
}

// ---------------------------------------------------------------- decoder (MFMA, K=192 hi/lo trick)
// softplus via raw v_exp_f32/v_log_f32: max(x,0) + ln2*log2(1 + 2^(-log2e*|x|)).
// ~8 VALU insts vs ~30 for expf+log1pf; |err| ~1e-7 << bf16-split error.
__device__ __forceinline__ float softplus_fast(float x) {
    float e = __builtin_amdgcn_exp2f(-1.4426950408889634f * fabsf(x));
    float l = 0.6931471805599453f * __builtin_amdgcn_logf(1.0f + e);
    return fmaxf(x, 0.0f) + l;
}

__global__ __launch_bounds__(256) void k_dec(const unsigned short* __restrict__ zhi,
                                             const unsigned short* __restrict__ zlo,
                                             const float* __restrict__ dbias,
                                             float* __restrict__ out) {
    // LDS: per tile 128 rows x 128 bf16 (hi 64 | lo 64), 16B chunks XOR-swizzled by row&15.
    // After compute, the same 64KB is reused as a 128x128 f32 staging tile for
    // fully-coalesced dwordx4 output stores (kills partial-line RMW fetches).
    union DecSmem {
        struct { short A[128 * 128]; short B[128 * 128]; } ab;
        float C[128 * 128];
    };
    __shared__ DecSmem sm;
    int tid = threadIdx.x;
    int r0 = blockIdx.y * 128, c0 = blockIdx.x * 128;
    const float4* zh4 = (const float4*)zhi;
    const float4* zl4 = (const float4*)zlo;
#pragma unroll
    for (int p8 = 0; p8 < 8; ++p8) {
        int idx = p8 * 256 + tid;
        int row = idx >> 4, c = idx & 15;
        float4 va = (c < 8) ? zh4[(size_t)(r0 + row) * 8 + c] : zl4[(size_t)(r0 + row) * 8 + (c - 8)];
        float4 vb = (c < 8) ? zh4[(size_t)(c0 + row) * 8 + c] : zl4[(size_t)(c0 + row) * 8 + (c - 8)];
        int pos = c ^ (row & 15);
        *(float4*)&sm.ab.A[row * 128 + pos * 8] = va;
        *(float4*)&sm.ab.B[row * 128 + pos * 8] = vb;
    }
    __syncthreads();
    int lane = tid & 63, w = tid >> 6;
    int r = lane & 15, q = lane >> 4;
    f32x4 acc[2][8];
#pragma unroll
    for (int mt = 0; mt < 2; ++mt)
#pragma unroll
        for (int nt = 0; nt < 8; ++nt) acc[mt][nt] = (f32x4){0.f, 0.f, 0.f, 0.f};
    // K=192: A chunks [hi0,hi1,hi0,hi1,lo0,lo1] ; B chunks [hi0,hi1,lo0,lo1,hi0,hi1]
    const int aSel[6] = {0, 4, 0, 4, 8, 12};
    const int bSel[6] = {0, 4, 8, 12, 0, 4};
#pragma unroll
    for (int ks = 0; ks < 6; ++ks) {
        short8 af[2], bf[8];
#pragma unroll
        for (int mt = 0; mt < 2; ++mt) {
            int rowA = w * 32 + mt * 16 + r;
            af[mt] = *(const short8*)&sm.ab.A[rowA * 128 + ((aSel[ks] + q) ^ r) * 8];
        }
#pragma unroll
        for (int nt = 0; nt < 8; ++nt) {
            int rowB = nt * 16 + r;
            bf[nt] = *(const short8*)&sm.ab.B[rowB * 128 + ((bSel[ks] + q) ^ r) * 8];
        }
#pragma unroll
        for (int mt = 0; mt < 2; ++mt)
#pragma unroll
            for (int nt = 0; nt < 8; ++nt)
                acc[mt][nt] = __builtin_amdgcn_mfma_f32_16x16x32_bf16(af[mt], bf[nt], acc[mt][nt], 0, 0, 0);
    }
    float db = dbias[0];
    __syncthreads();   // done reading A/B fragments; LDS now becomes the C tile
    // stage softplus'd results into LDS: col swizzled by XOR bit4 with row bit2
    // (write: 2-way bank alias = free; read: float4-aligned permutation)
#pragma unroll
    for (int mt = 0; mt < 2; ++mt) {
        int rowb = w * 32 + mt * 16 + q * 4;
#pragma unroll
        for (int nt = 0; nt < 8; ++nt) {
            int col = nt * 16 + r;
#pragma unroll
            for (int reg = 0; reg < 4; ++reg) {
                int row = rowb + reg;
                sm.C[row * 128 + (col ^ ((row & 4) << 2))] = softplus_fast(acc[mt][nt][reg] + db);
            }
        }
    }
    __syncthreads();
    bool full = (r0 + 128 <= NNODES) && (c0 + 128 <= NNODES);
    if (full) {
        // 4096 float4 chunks, 16 per thread; consecutive lanes -> consecutive 16B
        // -> 1KB contiguous per wave-store, full 128B lines, zero RMW.
#pragma unroll
        for (int p = 0; p < 16; ++p) {
            int idx = p * 256 + tid;
            int row = idx >> 5, k = idx & 31;
            float4 v = *(const float4*)&sm.C[row * 128 + ((k * 4) ^ ((row & 4) << 2))];
            *(float4*)&out[(size_t)(r0 + row) * NNODES + c0 + k * 4] = v;
        }
    } else {
        for (int p = 0; p < 16; ++p) {
            int idx = p * 256 + tid;
            int row = idx >> 5, k = idx & 31;
            int gr = r0 + row;
            int gc = c0 + k * 4;
            if (gr >= NNODES || gc >= NNODES) continue;
            float4 v = *(const float4*)&sm.C[row * 128 + ((k * 4) ^ ((row & 4) << 2))];
            if (gc + 4 <= NNODES) {
                *(float4*)&out[(size_t)gr * NNODES + gc] = v;
            } else {
                float vv[4] = {v.x, v.y, v.z, v.w};
                for (int j = 0; j < 4 && gc + j < NNODES; ++j)
                    out[(size_t)gr * NNODES + gc + j] = vv[j];
            }
        }
    }
}

// ---------------------------------------------------------------- launch
extern "C" void kernel_launch(void* const* d_in, const int* in_sizes, int n_in,
                              void* d_out, int out_size, void* d_ws, size_t ws_size,
                              hipStream_t stream) {
    const float* x_seq = (const float*)d_in[0];
    const int*   eidx  = (const int*)d_in[1];
    const float* ew    = (const float*)d_in[2];
    const float* W1    = (const float*)d_in[3];
    const float* b1    = (const float*)d_in[4];
    const float* W2    = (const float*)d_in[5];
    const float* b2    = (const float*)d_in[6];
    const float* W_ih  = (const float*)d_in[7];
    const float* W_hh  = (const float*)d_in[8];
    const float* b_ih  = (const float*)d_in[9];
    const float* b_hh  = (const float*)d_in[10];
    const float* dbias = (const float*)d_in[11];
    float* out = (float*)d_out;

    char* wsp = (char*)d_ws;
    auto alloc = [&](size_t bytes) {
        char* p = wsp;
        wsp += (bytes + 255) & ~(size_t)255;
        return p;
    };
    float* deg    = (float*)alloc((size_t)NNODES * 4);
    float* dinv   = (float*)alloc((size_t)NNODES * 4);
    int*   cnt    = (int*)alloc((size_t)NNODES * 4);
    int*   offs   = (int*)alloc((size_t)(NNODES + 1) * 4);
    int*   cursor = (int*)alloc((size_t)NNODES * 4);
    int*   srcb   = (int*)alloc((size_t)(NEDGES + NNODES) * 4);
    float* wnb    = (float*)alloc((size_t)(NEDGES + NNODES) * 4);
    float* hst    = (float*)alloc((size_t)NNODES * EMB * 4);
    unsigned short* zhi = (unsigned short*)alloc((size_t)NPAD * EMB * 2);
    unsigned short* zlo = (unsigned short*)alloc((size_t)NPAD * EMB * 2);
    float* Buf1   = (float*)alloc((size_t)T_STEPS * NNODES * G3 * 4);   // 92.2 MB
    float* Buf2   = (float*)alloc((size_t)T_STEPS * NNODES * HID * 4);  // 61.4 MB

    const int M = T_STEPS * NNODES;   // 120000

    k_setup<<<(NNODES + 255) / 256, 256, 0, stream>>>(deg, cnt);
    k_edge<<<(NEDGES + 255) / 256, 256, 0, stream>>>(eidx, ew, deg, cnt);
    k_dinv<<<(NNODES + 255) / 256, 256, 0, stream>>>(deg, dinv);
    k_scan<<<1, 1024, 0, stream>>>(cnt, offs, cursor);
    k_scatter<<<(NEDGES + NNODES + 255) / 256, 256, 0, stream>>>(eidx, ew, dinv, cursor, srcb, wnb);

    // GCN layer 1: Buf1 = x@W1 (rows permuted to [n][t]); Buf2 = relu(agg(Buf1)+b1)
    k_mm<64, 128, 2, 8, true, false, true><<<1024, 256, 0, stream>>>(x_seq, W1, nullptr, Buf1, M);
    k_agg<128, true><<<(NNODES * 64 + 255) / 256, 256, 0, stream>>>(Buf1, srcb, wnb, offs, b1, Buf2);
    // GCN layer 2: Buf1 = Buf2@W2 ; Buf2 = agg(Buf1)+b2  (= z_seq, [n][t][64])
    k_mm<128, 64, 4, 8, true, false, false><<<1024, 256, 0, stream>>>(Buf2, W2, nullptr, Buf1, M);
    k_agg<64, false><<<(NNODES * 64 + 255) / 256, 256, 0, stream>>>(Buf1, srcb, wnb, offs, b2, Buf2);
    // GRU input gates for all t: Buf1 = z_seq @ W_ih^T + b_ih  [n][t][192]
    k_mm<64, 192, 1, 8, false, true, false><<<1024, 192, 0, stream>>>(Buf2, W_ih, b_ih, Buf1, M);
    // Fused 12-step GRU, h resident in LDS, W_hh in registers
    k_gru<<<(NNODES + 5) / 6, 192, 0, stream>>>(Buf1, W_hh, b_hh, hst);
    k_zcopy<<<(NNODES * EMB + 255) / 256, 256, 0, stream>>>(hst, out);
    k_zsplit<<<(NPAD * EMB + 255) / 256, 256, 0, stream>>>(hst, zhi, zlo);
    dim3 gdec(NPAD / 128, NPAD / 128);
    k_dec<<<gdec, 256, 0, stream>>>(zhi, zlo, dbias, out);
}

// Round 4
// 1210.050 us; speedup vs baseline: 1.5745x; 1.0604x over previous
//
#include <hip/hip_runtime.h>
#include <cstdint>
#include <cstddef>

#define T_STEPS 12
#define NNODES  10000
#define NEDGES  320000
#define IN_DIM  64
#define HID     128
#define EMB     64
#define G3      192
#define NPAD    10112   // 79*128, decoder tile padding

typedef __attribute__((ext_vector_type(8))) short short8;
typedef __attribute__((ext_vector_type(4))) float f32x4;

// ---------------------------------------------------------------- setup / CSR
__global__ void k_setup(float* __restrict__ deg, int* __restrict__ cnt) {
    int i = blockIdx.x * 256 + threadIdx.x;
    if (i < NNODES) { deg[i] = 1.0f; cnt[i] = 1; }   // self-loop weight 1, count 1
}

__global__ void k_edge(const int* __restrict__ eidx, const float* __restrict__ ew,
                       float* __restrict__ deg, int* __restrict__ cnt) {
    int e = blockIdx.x * 256 + threadIdx.x;
    if (e >= NEDGES) return;
    int c = eidx[NEDGES + e];          // col
    atomicAdd(&deg[c], ew[e]);
    atomicAdd(&cnt[c], 1);
}

__global__ void k_dinv(const float* __restrict__ deg, float* __restrict__ dinv) {
    int i = blockIdx.x * 256 + threadIdx.x;
    if (i >= NNODES) return;
    float d = deg[i];
    dinv[i] = (d > 0.0f) ? rsqrtf(d) : 0.0f;
}

__global__ __launch_bounds__(1024) void k_scan(const int* __restrict__ cnt,
                                               int* __restrict__ offs, int* __restrict__ cursor) {
    __shared__ int sh[1024];
    int t = threadIdx.x;
    int loc[10];
    int run = 0;
#pragma unroll
    for (int i = 0; i < 10; ++i) {
        int idx = t * 10 + i;
        int v = (idx < NNODES) ? cnt[idx] : 0;
        loc[i] = run;
        run += v;
    }
    sh[t] = run;
    __syncthreads();
    for (int off = 1; off < 1024; off <<= 1) {
        int v = 0;
        if (t >= off) v = sh[t - off];
        __syncthreads();
        if (t >= off) sh[t] += v;
        __syncthreads();
    }
    int base = (t > 0) ? sh[t - 1] : 0;
#pragma unroll
    for (int i = 0; i < 10; ++i) {
        int idx = t * 10 + i;
        if (idx < NNODES) {
            int e = base + loc[i];
            offs[idx] = e;
            cursor[idx] = e;
        }
    }
    if (t == 1023) offs[NNODES] = sh[1023];
}

// packed edge record: (src, norm-weight)
__global__ void k_scatter(const int* __restrict__ eidx, const float* __restrict__ ew,
                          const float* __restrict__ dinv, int* __restrict__ cursor,
                          int2* __restrict__ edata) {
    int e = blockIdx.x * 256 + threadIdx.x;
    if (e < NEDGES) {
        int r = eidx[e];
        int c = eidx[NEDGES + e];
        float w = dinv[r] * ew[e] * dinv[c];
        int p = atomicAdd(&cursor[c], 1);
        edata[p] = make_int2(r, __float_as_int(w));
    } else if (e < NEDGES + NNODES) {
        int i = e - NEDGES;
        float di = dinv[i];
        int p = atomicAdd(&cursor[i], 1);
        edata[p] = make_int2(i, __float_as_int(di * di));
    }
}

// ---------------------------------------------------------------- small GEMM
// C[M,NO] = act(A[M,K] @ B + optional bias). BT=true: B stored [K,NO] row-major.
// BT=false: B stored [NO,K] (computes A @ B^T).
template <int K, int NO, int GR, int RPT, bool BT, bool BIAS, bool RELU>
__global__ __launch_bounds__(NO* GR) void k_mm(const float* __restrict__ A,
                                               const float* __restrict__ B,
                                               const float* __restrict__ bias,
                                               float* __restrict__ C, int M) {
    constexpr int NOP = NO + 1;
    __shared__ float Bs[K * NOP];   // [k][c]
    const int tid = threadIdx.x;
    constexpr int NTHR = NO * GR;
    for (int i = tid; i < K * NO; i += NTHR) {
        if (BT) { int k = i / NO, c = i - k * NO; Bs[k * NOP + c] = B[i]; }
        else    { int c = i / K,  k = i - c * K;  Bs[k * NOP + c] = B[i]; }
    }
    __syncthreads();
    const int c  = tid % NO;
    const int rg = tid / NO;
    const float bv = BIAS ? bias[c] : 0.0f;
    for (int r0 = (blockIdx.x * GR + rg) * RPT; r0 < M; r0 += gridDim.x * GR * RPT) {
        int r0u = __builtin_amdgcn_readfirstlane(r0);
        float acc[RPT];
#pragma unroll
        for (int i = 0; i < RPT; ++i) acc[i] = bv;
        const float4* A4 = (const float4*)A + (size_t)r0u * (K / 4);
        for (int k0 = 0; k0 < K; k0 += 4) {
            float a[RPT][4];
#pragma unroll
            for (int i = 0; i < RPT; ++i) {
                float4 v = A4[i * (K / 4) + (k0 >> 2)];
                a[i][0] = v.x; a[i][1] = v.y; a[i][2] = v.z; a[i][3] = v.w;
            }
#pragma unroll
            for (int j = 0; j < 4; ++j) {
                float b = Bs[(k0 + j) * NOP + c];
#pragma unroll
                for (int i = 0; i < RPT; ++i) acc[i] = fmaf(a[i][j], b, acc[i]);
            }
        }
#pragma unroll
        for (int i = 0; i < RPT; ++i) {
            float v = acc[i];
            if (RELU) v = fmaxf(v, 0.0f);
            C[(size_t)(r0 + i) * NO + c] = v;
        }
    }
}

// ---------------------------------------------------------------- aggregation (per-t, F=64)
// t-major layout [t][n][64]. grid = (nodes/4, T). Blocks sharing t run ~concurrently,
// so the gather working set is one 2.56 MB t-slab -> fits per-XCD 4 MB L2.
template <bool BIAS>
__global__ __launch_bounds__(256) void k_aggt(const float* __restrict__ H,     // [T][N][64]
                                              const int2* __restrict__ edata,
                                              const int* __restrict__ offs,
                                              const float* __restrict__ bias,
                                              float* __restrict__ out) {       // [T][N][64]
    int node = (blockIdx.x * 256 + threadIdx.x) >> 6;
    node = __builtin_amdgcn_readfirstlane(node);
    if (node >= NNODES) return;
    int t = blockIdx.y;
    int lane = threadIdx.x & 63;
    const float* Ht = H + (size_t)t * (NNODES * EMB);
    int beg = offs[node], end = offs[node + 1];
    float acc = BIAS ? bias[lane] : 0.0f;
    for (int e0 = beg; e0 < end; e0 += 64) {
        int idx = e0 + lane;
        int2 ed = (idx < end) ? edata[idx] : make_int2(0, 0);
        int sv = ed.x;
        float wv = __int_as_float(ed.y);
        int m = min(64, end - e0);
#pragma unroll 4
        for (int j = 0; j < m; ++j) {
            int sj = __shfl(sv, j);
            float wj = __shfl(wv, j);
            acc = fmaf(wj, Ht[sj * EMB + lane], acc);
        }
    }
    out[(size_t)t * (NNODES * EMB) + (size_t)node * EMB + lane] = acc;
}

// ---------------------------------------------------------------- fused GRU (all 12 steps)
// gi layout: [t][node][192] (t-major). Each block owns RPB=6 rows for the whole sequence.
// W_hh row lives in REGISTERS (one output column c per thread, t-invariant).
__global__ __launch_bounds__(192, 3) void k_gru(const float* __restrict__ gi,
                                                const float* __restrict__ W_hh,  // [192,64]
                                                const float* __restrict__ b_hh,
                                                float* __restrict__ hout) {      // [N,64]
    constexpr int RPB = 6;
    __shared__ float ghs[RPB][G3 + 1];   // 4632 B
    __shared__ float hs[RPB][64];        // 1536 B  -> total 6168 B
    int tid = threadIdx.x;
    // hoist this thread's W_hh row (64 floats) into registers, t-invariant
    float wv[64];
    const float4* W4 = (const float4*)(W_hh + (size_t)tid * 64);
#pragma unroll
    for (int j = 0; j < 16; ++j) {
        float4 v = W4[j];
        wv[4 * j + 0] = v.x; wv[4 * j + 1] = v.y;
        wv[4 * j + 2] = v.z; wv[4 * j + 3] = v.w;
    }
    for (int i = tid; i < RPB * 64; i += 192) ((float*)hs)[i] = 0.0f;
    __syncthreads();
    int r0 = blockIdx.x * RPB;
    float bh = b_hh[tid];
    for (int t = 0; t < T_STEPS; ++t) {
        float acc[RPB];
#pragma unroll
        for (int i = 0; i < RPB; ++i) acc[i] = bh;
#pragma unroll
        for (int k0 = 0; k0 < 64; k0 += 4) {
#pragma unroll
            for (int i = 0; i < RPB; ++i) {
                float4 h4 = *(const float4*)&hs[i][k0];   // broadcast ds_read_b128
                acc[i] = fmaf(h4.x, wv[k0 + 0], acc[i]);
                acc[i] = fmaf(h4.y, wv[k0 + 1], acc[i]);
                acc[i] = fmaf(h4.z, wv[k0 + 2], acc[i]);
                acc[i] = fmaf(h4.w, wv[k0 + 3], acc[i]);
            }
        }
#pragma unroll
        for (int i = 0; i < RPB; ++i) ghs[i][tid] = acc[i];
        __syncthreads();
#pragma unroll
        for (int it = 0; it < 2; ++it) {
            int item = it * 192 + tid;        // 0..383, exactly 2 full passes
            int rr = item >> 6, f = item & 63;
            int grow = r0 + rr;
            if (grow < NNODES) {
                const float* gir = gi + ((size_t)t * NNODES + grow) * G3;
                float ir = gir[f], iz = gir[64 + f], inn = gir[128 + f];
                float hr = ghs[rr][f], hz = ghs[rr][64 + f], hn = ghs[rr][128 + f];
                float rg = 1.0f / (1.0f + expf(-(ir + hr)));
                float zg = 1.0f / (1.0f + expf(-(iz + hz)));
                float ng = tanhf(fmaf(rg, hn, inn));
                float hp = hs[rr][f];
                hs[rr][f] = fmaf(zg, hp - ng, ng);    // (1-z)*n + z*h
            }
        }
        __syncthreads();
    }
#pragma unroll
    for (int it = 0; it < 2; ++it) {
        int item = it * 192 + tid;
        int rr = item >> 6, f = item & 63;
        int grow = r0 + rr;
        if (grow < NNODES) hout[(size_t)grow * 64 + f] = hs[rr][f];
    }
}

__global__ void k_zcopy(const float* __restrict__ h, float* __restrict__ out) {
    int i = blockIdx.x * 256 + threadIdx.x;
    if (i < NNODES * EMB) out[(size_t)NNODES * NNODES + i] = h[i];
}

// ---------------------------------------------------------------- bf16 hi/lo split
__global__ void k_zsplit(const float* __restrict__ h,
                         unsigned short* __restrict__ zhi, unsigned short* __restrict__ zlo) {
    int i = blockIdx.x * 256 + threadIdx.x;
    if (i >= NPAD * EMB) return;
    float x = (i < NNODES * EMB) ? h[i] : 0.0f;
    uint32_t b = __float_as_uint(x);
    uint32_t rh = (b + 0x7FFFu + ((b >> 16) & 1u)) & 0xFFFF0000u;   // RNE bf16 of x
    float fhi = __uint_as_float(rh);
    float lo = x - fhi;
    uint32_t bl = __float_as_uint(lo);
    uint32_t rl = (bl + 0x7FFFu + ((bl >> 16) & 1u)) & 0xFFFF0000u;
    zhi[i] = (unsigned short)(rh >> 16);
    zlo[i] = (unsigned short)(rl >> 16);
}

// ---------------------------------------------------------------- decoder (MFMA, K=192 hi/lo trick)
// softplus via raw v_exp_f32/v_log_f32: max(x,0) + ln2*log2(1 + 2^(-log2e*|x|)).
// ~8 VALU insts vs ~30 for expf+log1pf; |err| ~1e-7 << bf16-split error.
__device__ __forceinline__ float softplus_fast(float x) {
    float e = __builtin_amdgcn_exp2f(-1.4426950408889634f * fabsf(x));
    float l = 0.6931471805599453f * __builtin_amdgcn_logf(1.0f + e);
    return fmaxf(x, 0.0f) + l;
}

__global__ __launch_bounds__(256) void k_dec(const unsigned short* __restrict__ zhi,
                                             const unsigned short* __restrict__ zlo,
                                             const float* __restrict__ dbias,
                                             float* __restrict__ out) {
    // LDS: per tile 128 rows x 128 bf16 (hi 64 | lo 64), 16B chunks XOR-swizzled by row&15.
    // After compute, the same 64KB is reused as a 128x128 f32 staging tile for
    // fully-coalesced dwordx4 output stores (kills partial-line RMW fetches).
    union DecSmem {
        struct { short A[128 * 128]; short B[128 * 128]; } ab;
        float C[128 * 128];
    };
    __shared__ DecSmem sm;
    int tid = threadIdx.x;
    int r0 = blockIdx.y * 128, c0 = blockIdx.x * 128;
    const float4* zh4 = (const float4*)zhi;
    const float4* zl4 = (const float4*)zlo;
#pragma unroll
    for (int p8 = 0; p8 < 8; ++p8) {
        int idx = p8 * 256 + tid;
        int row = idx >> 4, c = idx & 15;
        float4 va = (c < 8) ? zh4[(size_t)(r0 + row) * 8 + c] : zl4[(size_t)(r0 + row) * 8 + (c - 8)];
        float4 vb = (c < 8) ? zh4[(size_t)(c0 + row) * 8 + c] : zl4[(size_t)(c0 + row) * 8 + (c - 8)];
        int pos = c ^ (row & 15);
        *(float4*)&sm.ab.A[row * 128 + pos * 8] = va;
        *(float4*)&sm.ab.B[row * 128 + pos * 8] = vb;
    }
    __syncthreads();
    int lane = tid & 63, w = tid >> 6;
    int r = lane & 15, q = lane >> 4;
    f32x4 acc[2][8];
#pragma unroll
    for (int mt = 0; mt < 2; ++mt)
#pragma unroll
        for (int nt = 0; nt < 8; ++nt) acc[mt][nt] = (f32x4){0.f, 0.f, 0.f, 0.f};
    // K=192: A chunks [hi0,hi1,hi0,hi1,lo0,lo1] ; B chunks [hi0,hi1,lo0,lo1,hi0,hi1]
    const int aSel[6] = {0, 4, 0, 4, 8, 12};
    const int bSel[6] = {0, 4, 8, 12, 0, 4};
#pragma unroll
    for (int ks = 0; ks < 6; ++ks) {
        short8 af[2], bf[8];
#pragma unroll
        for (int mt = 0; mt < 2; ++mt) {
            int rowA = w * 32 + mt * 16 + r;
            af[mt] = *(const short8*)&sm.ab.A[rowA * 128 + ((aSel[ks] + q) ^ r) * 8];
        }
#pragma unroll
        for (int nt = 0; nt < 8; ++nt) {
            int rowB = nt * 16 + r;
            bf[nt] = *(const short8*)&sm.ab.B[rowB * 128 + ((bSel[ks] + q) ^ r) * 8];
        }
#pragma unroll
        for (int mt = 0; mt < 2; ++mt)
#pragma unroll
            for (int nt = 0; nt < 8; ++nt)
                acc[mt][nt] = __builtin_amdgcn_mfma_f32_16x16x32_bf16(af[mt], bf[nt], acc[mt][nt], 0, 0, 0);
    }
    float db = dbias[0];
    __syncthreads();   // done reading A/B fragments; LDS now becomes the C tile
    // stage softplus'd results into LDS: col swizzled by XOR bit4 with row bit2
    // (write: 2-way bank alias = free; read: float4-aligned permutation)
#pragma unroll
    for (int mt = 0; mt < 2; ++mt) {
        int rowb = w * 32 + mt * 16 + q * 4;
#pragma unroll
        for (int nt = 0; nt < 8; ++nt) {
            int col = nt * 16 + r;
#pragma unroll
            for (int reg = 0; reg < 4; ++reg) {
                int row = rowb + reg;
                sm.C[row * 128 + (col ^ ((row & 4) << 2))] = softplus_fast(acc[mt][nt][reg] + db);
            }
        }
    }
    __syncthreads();
    bool full = (r0 + 128 <= NNODES) && (c0 + 128 <= NNODES);
    if (full) {
        // 4096 float4 chunks, 16 per thread; consecutive lanes -> consecutive 16B
        // -> 1KB contiguous per wave-store, full 128B lines, zero RMW.
#pragma unroll
        for (int p = 0; p < 16; ++p) {
            int idx = p * 256 + tid;
            int row = idx >> 5, k = idx & 31;
            float4 v = *(const float4*)&sm.C[row * 128 + ((k * 4) ^ ((row & 4) << 2))];
            *(float4*)&out[(size_t)(r0 + row) * NNODES + c0 + k * 4] = v;
        }
    } else {
        for (int p = 0; p < 16; ++p) {
            int idx = p * 256 + tid;
            int row = idx >> 5, k = idx & 31;
            int gr = r0 + row;
            int gc = c0 + k * 4;
            if (gr >= NNODES || gc >= NNODES) continue;
            float4 v = *(const float4*)&sm.C[row * 128 + ((k * 4) ^ ((row & 4) << 2))];
            if (gc + 4 <= NNODES) {
                *(float4*)&out[(size_t)gr * NNODES + gc] = v;
            } else {
                float vv[4] = {v.x, v.y, v.z, v.w};
                for (int j = 0; j < 4 && gc + j < NNODES; ++j)
                    out[(size_t)gr * NNODES + gc + j] = vv[j];
            }
        }
    }
}

// ---------------------------------------------------------------- launch
extern "C" void kernel_launch(void* const* d_in, const int* in_sizes, int n_in,
                              void* d_out, int out_size, void* d_ws, size_t ws_size,
                              hipStream_t stream) {
    const float* x_seq = (const float*)d_in[0];
    const int*   eidx  = (const int*)d_in[1];
    const float* ew    = (const float*)d_in[2];
    const float* W1    = (const float*)d_in[3];
    const float* b1    = (const float*)d_in[4];
    const float* W2    = (const float*)d_in[5];
    const float* b2    = (const float*)d_in[6];
    const float* W_ih  = (const float*)d_in[7];
    const float* W_hh  = (const float*)d_in[8];
    const float* b_ih  = (const float*)d_in[9];
    const float* b_hh  = (const float*)d_in[10];
    const float* dbias = (const float*)d_in[11];
    float* out = (float*)d_out;

    char* wsp = (char*)d_ws;
    auto alloc = [&](size_t bytes) {
        char* p = wsp;
        wsp += (bytes + 255) & ~(size_t)255;
        return p;
    };
    float* deg    = (float*)alloc((size_t)NNODES * 4);
    float* dinv   = (float*)alloc((size_t)NNODES * 4);
    int*   cnt    = (int*)alloc((size_t)NNODES * 4);
    int*   offs   = (int*)alloc((size_t)(NNODES + 1) * 4);
    int*   cursor = (int*)alloc((size_t)NNODES * 4);
    int2*  edata  = (int2*)alloc((size_t)(NEDGES + NNODES) * 8);
    float* hst    = (float*)alloc((size_t)NNODES * EMB * 4);
    unsigned short* zhi = (unsigned short*)alloc((size_t)NPAD * EMB * 2);
    unsigned short* zlo = (unsigned short*)alloc((size_t)NPAD * EMB * 2);
    float* Buf1   = (float*)alloc((size_t)T_STEPS * NNODES * G3 * 4);   // 92.2 MB
    float* Buf2   = (float*)alloc((size_t)T_STEPS * NNODES * HID * 4);  // 61.4 MB

    const int M = T_STEPS * NNODES;   // 120000
    // Buf2 partitions (t-major [t][n][F]):
    float* xa = Buf2;                                   // [T][N][64]  30.7 MB
    float* g2 = Buf2 + (size_t)T_STEPS * NNODES * EMB;  // [T][N][64]  30.7 MB
    float* z  = Buf2;                                   // reuse xa region (dead)
    float* h1 = Buf1;                                   // [T][N][128] 61.4 MB
    float* gi = Buf1;                                   // [T][N][192] 92.2 MB (h1 dead)

    k_setup<<<(NNODES + 255) / 256, 256, 0, stream>>>(deg, cnt);
    k_edge<<<(NEDGES + 255) / 256, 256, 0, stream>>>(eidx, ew, deg, cnt);
    k_dinv<<<(NNODES + 255) / 256, 256, 0, stream>>>(deg, dinv);
    k_scan<<<1, 1024, 0, stream>>>(cnt, offs, cursor);
    k_scatter<<<(NEDGES + NNODES + 255) / 256, 256, 0, stream>>>(eidx, ew, dinv, cursor, edata);

    dim3 gagg((NNODES * 64 + 255) / 256, T_STEPS);
    // layer 1: agg(x) then relu(.@W1 + b1)    [agg(x@W1) == agg(x)@W1]
    k_aggt<false><<<gagg, 256, 0, stream>>>(x_seq, edata, offs, nullptr, xa);
    k_mm<64, 128, 2, 8, true, true, true><<<1024, 256, 0, stream>>>(xa, W1, b1, h1, M);
    // layer 2: g2 = h1@W2 ; z = agg(g2) + b2
    k_mm<128, 64, 4, 8, true, false, false><<<1024, 256, 0, stream>>>(h1, W2, nullptr, g2, M);
    k_aggt<true><<<gagg, 256, 0, stream>>>(g2, edata, offs, b2, z);
    // GRU input gates for all t: gi = z @ W_ih^T + b_ih  [t][n][192]
    k_mm<64, 192, 1, 8, false, true, false><<<1024, 192, 0, stream>>>(z, W_ih, b_ih, gi, M);
    // Fused 12-step GRU, h resident in LDS, W_hh in registers
    k_gru<<<(NNODES + 5) / 6, 192, 0, stream>>>(gi, W_hh, b_hh, hst);
    k_zcopy<<<(NNODES * EMB + 255) / 256, 256, 0, stream>>>(hst, out);
    k_zsplit<<<(NPAD * EMB + 255) / 256, 256, 0, stream>>>(hst, zhi, zlo);
    dim3 gdec(NPAD / 128, NPAD / 128);
    k_dec<<<gdec, 256, 0, stream>>>(zhi, zlo, dbias, out);
}

// Round 5
// 1129.072 us; speedup vs baseline: 1.6874x; 1.0717x over previous
//
#include <hip/hip_runtime.h>
#include <cstdint>
#include <cstddef>

#define T_STEPS 12
#define NNODES  10000
#define NEDGES  320000
#define IN_DIM  64
#define HID     128
#define EMB     64
#define G3      192
#define NPAD    10112   // 79*128, decoder tile padding

typedef __attribute__((ext_vector_type(8))) short short8;
typedef __attribute__((ext_vector_type(4))) float f32x4;

// ---------------------------------------------------------------- setup / CSR
__global__ void k_setup(float* __restrict__ deg, int* __restrict__ cnt) {
    int i = blockIdx.x * 256 + threadIdx.x;
    if (i < NNODES) { deg[i] = 1.0f; cnt[i] = 1; }   // self-loop weight 1, count 1
}

__global__ void k_edge(const int* __restrict__ eidx, const float* __restrict__ ew,
                       float* __restrict__ deg, int* __restrict__ cnt) {
    int e = blockIdx.x * 256 + threadIdx.x;
    if (e >= NEDGES) return;
    int c = eidx[NEDGES + e];          // col
    atomicAdd(&deg[c], ew[e]);
    atomicAdd(&cnt[c], 1);
}

__global__ void k_dinv(const float* __restrict__ deg, float* __restrict__ dinv) {
    int i = blockIdx.x * 256 + threadIdx.x;
    if (i >= NNODES) return;
    float d = deg[i];
    dinv[i] = (d > 0.0f) ? rsqrtf(d) : 0.0f;
}

__global__ __launch_bounds__(1024) void k_scan(const int* __restrict__ cnt,
                                               int* __restrict__ offs, int* __restrict__ cursor) {
    __shared__ int sh[1024];
    int t = threadIdx.x;
    int loc[10];
    int run = 0;
#pragma unroll
    for (int i = 0; i < 10; ++i) {
        int idx = t * 10 + i;
        int v = (idx < NNODES) ? cnt[idx] : 0;
        loc[i] = run;
        run += v;
    }
    sh[t] = run;
    __syncthreads();
    for (int off = 1; off < 1024; off <<= 1) {
        int v = 0;
        if (t >= off) v = sh[t - off];
        __syncthreads();
        if (t >= off) sh[t] += v;
        __syncthreads();
    }
    int base = (t > 0) ? sh[t - 1] : 0;
#pragma unroll
    for (int i = 0; i < 10; ++i) {
        int idx = t * 10 + i;
        if (idx < NNODES) {
            int e = base + loc[i];
            offs[idx] = e;
            cursor[idx] = e;
        }
    }
    if (t == 1023) offs[NNODES] = sh[1023];
}

// packed edge record: (src, norm-weight)
__global__ void k_scatter(const int* __restrict__ eidx, const float* __restrict__ ew,
                          const float* __restrict__ dinv, int* __restrict__ cursor,
                          int2* __restrict__ edata) {
    int e = blockIdx.x * 256 + threadIdx.x;
    if (e < NEDGES) {
        int r = eidx[e];
        int c = eidx[NEDGES + e];
        float w = dinv[r] * ew[e] * dinv[c];
        int p = atomicAdd(&cursor[c], 1);
        edata[p] = make_int2(r, __float_as_int(w));
    } else if (e < NEDGES + NNODES) {
        int i = e - NEDGES;
        float di = dinv[i];
        int p = atomicAdd(&cursor[i], 1);
        edata[p] = make_int2(i, __float_as_int(di * di));
    }
}

// ---------------------------------------------------------------- small GEMM
// C[M,NO] = act(A[M,K] @ B + optional bias). BT=true: B stored [K,NO] row-major.
// BT=false: B stored [NO,K] (computes A @ B^T).
template <int K, int NO, int GR, int RPT, bool BT, bool BIAS, bool RELU>
__global__ __launch_bounds__(NO* GR) void k_mm(const float* __restrict__ A,
                                               const float* __restrict__ B,
                                               const float* __restrict__ bias,
                                               float* __restrict__ C, int M) {
    constexpr int NOP = NO + 1;
    __shared__ float Bs[K * NOP];   // [k][c]
    const int tid = threadIdx.x;
    constexpr int NTHR = NO * GR;
    for (int i = tid; i < K * NO; i += NTHR) {
        if (BT) { int k = i / NO, c = i - k * NO; Bs[k * NOP + c] = B[i]; }
        else    { int c = i / K,  k = i - c * K;  Bs[k * NOP + c] = B[i]; }
    }
    __syncthreads();
    const int c  = tid % NO;
    const int rg = tid / NO;
    const float bv = BIAS ? bias[c] : 0.0f;
    for (int r0 = (blockIdx.x * GR + rg) * RPT; r0 < M; r0 += gridDim.x * GR * RPT) {
        int r0u = __builtin_amdgcn_readfirstlane(r0);
        float acc[RPT];
#pragma unroll
        for (int i = 0; i < RPT; ++i) acc[i] = bv;
        const float4* A4 = (const float4*)A + (size_t)r0u * (K / 4);
        for (int k0 = 0; k0 < K; k0 += 4) {
            float a[RPT][4];
#pragma unroll
            for (int i = 0; i < RPT; ++i) {
                float4 v = A4[i * (K / 4) + (k0 >> 2)];
                a[i][0] = v.x; a[i][1] = v.y; a[i][2] = v.z; a[i][3] = v.w;
            }
#pragma unroll
            for (int j = 0; j < 4; ++j) {
                float b = Bs[(k0 + j) * NOP + c];
#pragma unroll
                for (int i = 0; i < RPT; ++i) acc[i] = fmaf(a[i][j], b, acc[i]);
            }
        }
#pragma unroll
        for (int i = 0; i < RPT; ++i) {
            float v = acc[i];
            if (RELU) v = fmaxf(v, 0.0f);
            C[(size_t)(r0 + i) * NO + c] = v;
        }
    }
}

// ---------------------------------------------------------------- aggregation (t-pair, F=64)
// t-major layout [t][n][64]. grid = (nodes/4, T/2): each wave gathers one node for a
// t-PAIR (edata read once per pair -> halves index stream). Blocks sharing a pair run
// ~concurrently: working set = 2 slabs (5.1 MB). Non-temporal edata loads and output
// stores keep the slabs resident in each XCD's 4 MB L2 (no stream pollution).
template <bool BIAS>
__global__ __launch_bounds__(256) void k_aggt(const float* __restrict__ H,     // [T][N][64]
                                              const int2* __restrict__ edata,
                                              const int* __restrict__ offs,
                                              const float* __restrict__ bias,
                                              float* __restrict__ out) {       // [T][N][64]
    int node = (blockIdx.x * 256 + threadIdx.x) >> 6;
    node = __builtin_amdgcn_readfirstlane(node);
    if (node >= NNODES) return;
    int t0 = blockIdx.y * 2;
    int lane = threadIdx.x & 63;
    const float* H0 = H + (size_t)t0 * (NNODES * EMB);
    const float* H1 = H0 + (size_t)(NNODES * EMB);
    int beg = offs[node], end = offs[node + 1];
    float bv = BIAS ? bias[lane] : 0.0f;
    float acc0 = bv, acc1 = bv;
    for (int e0 = beg; e0 < end; e0 += 64) {
        int idx = e0 + lane;
        unsigned long long ev = (idx < end)
            ? __builtin_nontemporal_load((const unsigned long long*)&edata[idx]) : 0ull;
        int sv = (int)(ev & 0xFFFFFFFFull);
        float wv = __int_as_float((int)(ev >> 32));
        int m = min(64, end - e0);
#pragma unroll 4
        for (int j = 0; j < m; ++j) {
            int sj = __shfl(sv, j);
            float wj = __shfl(wv, j);
            acc0 = fmaf(wj, H0[sj * EMB + lane], acc0);
            acc1 = fmaf(wj, H1[sj * EMB + lane], acc1);
        }
    }
    size_t o0 = (size_t)t0 * (NNODES * EMB) + (size_t)node * EMB + lane;
    __builtin_nontemporal_store(acc0, &out[o0]);
    __builtin_nontemporal_store(acc1, &out[o0 + (size_t)(NNODES * EMB)]);
}

// ---------------------------------------------------------------- fused GRU (all 12 steps)
// gi layout: [t][node][192] (t-major). Each block owns RPB=6 rows for the whole sequence.
// W_hh row lives in REGISTERS (one output column c per thread, t-invariant).
// Writes the final hidden state directly into the output tail (out + N*N).
__global__ __launch_bounds__(192, 3) void k_gru(const float* __restrict__ gi,
                                                const float* __restrict__ W_hh,  // [192,64]
                                                const float* __restrict__ b_hh,
                                                float* __restrict__ hout) {      // = out + N*N
    constexpr int RPB = 6;
    __shared__ float ghs[RPB][G3 + 1];   // 4632 B
    __shared__ float hs[RPB][64];        // 1536 B  -> total 6168 B
    int tid = threadIdx.x;
    // hoist this thread's W_hh row (64 floats) into registers, t-invariant
    float wv[64];
    const float4* W4 = (const float4*)(W_hh + (size_t)tid * 64);
#pragma unroll
    for (int j = 0; j < 16; ++j) {
        float4 v = W4[j];
        wv[4 * j + 0] = v.x; wv[4 * j + 1] = v.y;
        wv[4 * j + 2] = v.z; wv[4 * j + 3] = v.w;
    }
    for (int i = tid; i < RPB * 64; i += 192) ((float*)hs)[i] = 0.0f;
    __syncthreads();
    int r0 = blockIdx.x * RPB;
    float bh = b_hh[tid];
    for (int t = 0; t < T_STEPS; ++t) {
        float acc[RPB];
#pragma unroll
        for (int i = 0; i < RPB; ++i) acc[i] = bh;
#pragma unroll
        for (int k0 = 0; k0 < 64; k0 += 4) {
#pragma unroll
            for (int i = 0; i < RPB; ++i) {
                float4 h4 = *(const float4*)&hs[i][k0];   // broadcast ds_read_b128
                acc[i] = fmaf(h4.x, wv[k0 + 0], acc[i]);
                acc[i] = fmaf(h4.y, wv[k0 + 1], acc[i]);
                acc[i] = fmaf(h4.z, wv[k0 + 2], acc[i]);
                acc[i] = fmaf(h4.w, wv[k0 + 3], acc[i]);
            }
        }
#pragma unroll
        for (int i = 0; i < RPB; ++i) ghs[i][tid] = acc[i];
        __syncthreads();
#pragma unroll
        for (int it = 0; it < 2; ++it) {
            int item = it * 192 + tid;        // 0..383, exactly 2 full passes
            int rr = item >> 6, f = item & 63;
            int grow = r0 + rr;
            if (grow < NNODES) {
                const float* gir = gi + ((size_t)t * NNODES + grow) * G3;
                float ir = gir[f], iz = gir[64 + f], inn = gir[128 + f];
                float hr = ghs[rr][f], hz = ghs[rr][64 + f], hn = ghs[rr][128 + f];
                float rg = 1.0f / (1.0f + expf(-(ir + hr)));
                float zg = 1.0f / (1.0f + expf(-(iz + hz)));
                float ng = tanhf(fmaf(rg, hn, inn));
                float hp = hs[rr][f];
                hs[rr][f] = fmaf(zg, hp - ng, ng);    // (1-z)*n + z*h
            }
        }
        __syncthreads();
    }
#pragma unroll
    for (int it = 0; it < 2; ++it) {
        int item = it * 192 + tid;
        int rr = item >> 6, f = item & 63;
        int grow = r0 + rr;
        if (grow < NNODES) hout[(size_t)grow * 64 + f] = hs[rr][f];
    }
}

// ---------------------------------------------------------------- bf16 hi/lo split
__global__ void k_zsplit(const float* __restrict__ h,
                         unsigned short* __restrict__ zhi, unsigned short* __restrict__ zlo) {
    int i = blockIdx.x * 256 + threadIdx.x;
    if (i >= NPAD * EMB) return;
    float x = (i < NNODES * EMB) ? h[i] : 0.0f;
    uint32_t b = __float_as_uint(x);
    uint32_t rh = (b + 0x7FFFu + ((b >> 16) & 1u)) & 0xFFFF0000u;   // RNE bf16 of x
    float fhi = __uint_as_float(rh);
    float lo = x - fhi;
    uint32_t bl = __float_as_uint(lo);
    uint32_t rl = (bl + 0x7FFFu + ((bl >> 16) & 1u)) & 0xFFFF0000u;
    zhi[i] = (unsigned short)(rh >> 16);
    zlo[i] = (unsigned short)(rl >> 16);
}

// ---------------------------------------------------------------- decoder (MFMA, K=192 hi/lo trick)
// softplus via raw v_exp_f32/v_log_f32: max(x,0) + ln2*log2(1 + 2^(-log2e*|x|)).
// ~8 VALU insts vs ~30 for expf+log1pf; |err| ~1e-7 << bf16-split error.
__device__ __forceinline__ float softplus_fast(float x) {
    float e = __builtin_amdgcn_exp2f(-1.4426950408889634f * fabsf(x));
    float l = 0.6931471805599453f * __builtin_amdgcn_logf(1.0f + e);
    return fmaxf(x, 0.0f) + l;
}

__global__ __launch_bounds__(256) void k_dec(const unsigned short* __restrict__ zhi,
                                             const unsigned short* __restrict__ zlo,
                                             const float* __restrict__ dbias,
                                             float* __restrict__ out) {
    // LDS: per tile 128 rows x 128 bf16 (hi 64 | lo 64), 16B chunks XOR-swizzled by row&15.
    // After compute, the same 64KB is reused as a 128x128 f32 staging tile for
    // fully-coalesced dwordx4 output stores (kills partial-line RMW fetches).
    union DecSmem {
        struct { short A[128 * 128]; short B[128 * 128]; } ab;
        float C[128 * 128];
    };
    __shared__ DecSmem sm;
    int tid = threadIdx.x;
    int r0 = blockIdx.y * 128, c0 = blockIdx.x * 128;
    const float4* zh4 = (const float4*)zhi;
    const float4* zl4 = (const float4*)zlo;
#pragma unroll
    for (int p8 = 0; p8 < 8; ++p8) {
        int idx = p8 * 256 + tid;
        int row = idx >> 4, c = idx & 15;
        float4 va = (c < 8) ? zh4[(size_t)(r0 + row) * 8 + c] : zl4[(size_t)(r0 + row) * 8 + (c - 8)];
        float4 vb = (c < 8) ? zh4[(size_t)(c0 + row) * 8 + c] : zl4[(size_t)(c0 + row) * 8 + (c - 8)];
        int pos = c ^ (row & 15);
        *(float4*)&sm.ab.A[row * 128 + pos * 8] = va;
        *(float4*)&sm.ab.B[row * 128 + pos * 8] = vb;
    }
    __syncthreads();
    int lane = tid & 63, w = tid >> 6;
    int r = lane & 15, q = lane >> 4;
    f32x4 acc[2][8];
#pragma unroll
    for (int mt = 0; mt < 2; ++mt)
#pragma unroll
        for (int nt = 0; nt < 8; ++nt) acc[mt][nt] = (f32x4){0.f, 0.f, 0.f, 0.f};
    // K=192: A chunks [hi0,hi1,hi0,hi1,lo0,lo1] ; B chunks [hi0,hi1,lo0,lo1,hi0,hi1]
    const int aSel[6] = {0, 4, 0, 4, 8, 12};
    const int bSel[6] = {0, 4, 8, 12, 0, 4};
#pragma unroll
    for (int ks = 0; ks < 6; ++ks) {
        short8 af[2], bf[8];
#pragma unroll
        for (int mt = 0; mt < 2; ++mt) {
            int rowA = w * 32 + mt * 16 + r;
            af[mt] = *(const short8*)&sm.ab.A[rowA * 128 + ((aSel[ks] + q) ^ r) * 8];
        }
#pragma unroll
        for (int nt = 0; nt < 8; ++nt) {
            int rowB = nt * 16 + r;
            bf[nt] = *(const short8*)&sm.ab.B[rowB * 128 + ((bSel[ks] + q) ^ r) * 8];
        }
#pragma unroll
        for (int mt = 0; mt < 2; ++mt)
#pragma unroll
            for (int nt = 0; nt < 8; ++nt)
                acc[mt][nt] = __builtin_amdgcn_mfma_f32_16x16x32_bf16(af[mt], bf[nt], acc[mt][nt], 0, 0, 0);
    }
    float db = dbias[0];
    __syncthreads();   // done reading A/B fragments; LDS now becomes the C tile
    // stage softplus'd results into LDS: col swizzled by XOR bit4 with row bit2
    // (write: 2-way bank alias = free; read: float4-aligned permutation)
#pragma unroll
    for (int mt = 0; mt < 2; ++mt) {
        int rowb = w * 32 + mt * 16 + q * 4;
#pragma unroll
        for (int nt = 0; nt < 8; ++nt) {
            int col = nt * 16 + r;
#pragma unroll
            for (int reg = 0; reg < 4; ++reg) {
                int row = rowb + reg;
                sm.C[row * 128 + (col ^ ((row & 4) << 2))] = softplus_fast(acc[mt][nt][reg] + db);
            }
        }
    }
    __syncthreads();
    bool full = (r0 + 128 <= NNODES) && (c0 + 128 <= NNODES);
    if (full) {
        // 4096 float4 chunks, 16 per thread; consecutive lanes -> consecutive 16B
        // -> 1KB contiguous per wave-store, full 128B lines, zero RMW. Non-temporal:
        // out is write-once streaming; keeps zhi/zlo panels resident in L2.
#pragma unroll
        for (int p = 0; p < 16; ++p) {
            int idx = p * 256 + tid;
            int row = idx >> 5, k = idx & 31;
            f32x4 v = *(const f32x4*)&sm.C[row * 128 + ((k * 4) ^ ((row & 4) << 2))];
            __builtin_nontemporal_store(v, (f32x4*)&out[(size_t)(r0 + row) * NNODES + c0 + k * 4]);
        }
    } else {
        for (int p = 0; p < 16; ++p) {
            int idx = p * 256 + tid;
            int row = idx >> 5, k = idx & 31;
            int gr = r0 + row;
            int gc = c0 + k * 4;
            if (gr >= NNODES || gc >= NNODES) continue;
            float4 v = *(const float4*)&sm.C[row * 128 + ((k * 4) ^ ((row & 4) << 2))];
            if (gc + 4 <= NNODES) {
                *(float4*)&out[(size_t)gr * NNODES + gc] = v;
            } else {
                float vv[4] = {v.x, v.y, v.z, v.w};
                for (int j = 0; j < 4 && gc + j < NNODES; ++j)
                    out[(size_t)gr * NNODES + gc + j] = vv[j];
            }
        }
    }
}

// ---------------------------------------------------------------- launch
extern "C" void kernel_launch(void* const* d_in, const int* in_sizes, int n_in,
                              void* d_out, int out_size, void* d_ws, size_t ws_size,
                              hipStream_t stream) {
    const float* x_seq = (const float*)d_in[0];
    const int*   eidx  = (const int*)d_in[1];
    const float* ew    = (const float*)d_in[2];
    const float* W1    = (const float*)d_in[3];
    const float* b1    = (const float*)d_in[4];
    const float* W2    = (const float*)d_in[5];
    const float* b2    = (const float*)d_in[6];
    const float* W_ih  = (const float*)d_in[7];
    const float* W_hh  = (const float*)d_in[8];
    const float* b_ih  = (const float*)d_in[9];
    const float* b_hh  = (const float*)d_in[10];
    const float* dbias = (const float*)d_in[11];
    float* out = (float*)d_out;

    char* wsp = (char*)d_ws;
    auto alloc = [&](size_t bytes) {
        char* p = wsp;
        wsp += (bytes + 255) & ~(size_t)255;
        return p;
    };
    float* deg    = (float*)alloc((size_t)NNODES * 4);
    float* dinv   = (float*)alloc((size_t)NNODES * 4);
    int*   cnt    = (int*)alloc((size_t)NNODES * 4);
    int*   offs   = (int*)alloc((size_t)(NNODES + 1) * 4);
    int*   cursor = (int*)alloc((size_t)NNODES * 4);
    int2*  edata  = (int2*)alloc((size_t)(NEDGES + NNODES) * 8);
    unsigned short* zhi = (unsigned short*)alloc((size_t)NPAD * EMB * 2);
    unsigned short* zlo = (unsigned short*)alloc((size_t)NPAD * EMB * 2);
    float* Buf1   = (float*)alloc((size_t)T_STEPS * NNODES * G3 * 4);   // 92.2 MB
    float* Buf2   = (float*)alloc((size_t)T_STEPS * NNODES * HID * 4);  // 61.4 MB

    const int M = T_STEPS * NNODES;   // 120000
    // Buf2 partitions (t-major [t][n][F]):
    float* xa = Buf2;                                   // [T][N][64]  30.7 MB
    float* g2 = Buf2 + (size_t)T_STEPS * NNODES * EMB;  // [T][N][64]  30.7 MB
    float* z  = Buf2;                                   // reuse xa region (dead)
    float* h1 = Buf1;                                   // [T][N][128] 61.4 MB
    float* gi = Buf1;                                   // [T][N][192] 92.2 MB (h1 dead)
    float* hst = out + (size_t)NNODES * NNODES;         // embedding tail of output

    k_setup<<<(NNODES + 255) / 256, 256, 0, stream>>>(deg, cnt);
    k_edge<<<(NEDGES + 255) / 256, 256, 0, stream>>>(eidx, ew, deg, cnt);
    k_dinv<<<(NNODES + 255) / 256, 256, 0, stream>>>(deg, dinv);
    k_scan<<<1, 1024, 0, stream>>>(cnt, offs, cursor);
    k_scatter<<<(NEDGES + NNODES + 255) / 256, 256, 0, stream>>>(eidx, ew, dinv, cursor, edata);

    dim3 gagg((NNODES * 64 + 255) / 256, T_STEPS / 2);
    // layer 1: agg(x) then relu(.@W1 + b1)    [agg(x@W1) == agg(x)@W1]
    k_aggt<false><<<gagg, 256, 0, stream>>>(x_seq, edata, offs, nullptr, xa);
    k_mm<64, 128, 2, 8, true, true, true><<<1024, 256, 0, stream>>>(xa, W1, b1, h1, M);
    // layer 2: g2 = h1@W2 ; z = agg(g2) + b2
    k_mm<128, 64, 4, 8, true, false, false><<<1024, 256, 0, stream>>>(h1, W2, nullptr, g2, M);
    k_aggt<true><<<gagg, 256, 0, stream>>>(g2, edata, offs, b2, z);
    // GRU input gates for all t: gi = z @ W_ih^T + b_ih  [t][n][192]
    k_mm<64, 192, 1, 8, false, true, false><<<1024, 192, 0, stream>>>(z, W_ih, b_ih, gi, M);
    // Fused 12-step GRU, h resident in LDS, W_hh in registers; writes out-tail directly
    k_gru<<<(NNODES + 5) / 6, 192, 0, stream>>>(gi, W_hh, b_hh, hst);
    k_zsplit<<<(NPAD * EMB + 255) / 256, 256, 0, stream>>>(hst, zhi, zlo);
    dim3 gdec(NPAD / 128, NPAD / 128);
    k_dec<<<gdec, 256, 0, stream>>>(zhi, zlo, dbias, out);
}